// Round 1
// baseline (362.646 us; speedup 1.0000x reference)
//
#include <hip/hip_runtime.h>

#define NN 20000      // nodes
#define NE 320000     // edges
#define BB 16         // batch
#define PP 12         // periods
#define NCOL 384      // BB*PP*2 feature columns
#define OUT_OFF (BB*PP*NN)

// ---------------- small helpers ----------------
__device__ __forceinline__ float sigmoidf_(float v) {
    return __fdividef(1.f, 1.f + __expf(-v));
}
__device__ __forceinline__ float tanh_fast(float v) {
    v = fminf(fmaxf(v, -15.f), 15.f);
    float e = __expf(-2.f * v);
    return __fdividef(1.f - e, 1.f + e);
}

// ---------------- K1: init deg (self-loop weight 1) and counts ----------------
__global__ __launch_bounds__(256) void init_kernel(float* deg, int* cnt) {
    int i = blockIdx.x * 256 + threadIdx.x;
    if (i < NN) { deg[i] = 1.0f; cnt[i] = 0; }
}

// ---------------- K2: degree + per-dst edge count ----------------
__global__ __launch_bounds__(256) void degcnt_kernel(const int* __restrict__ ei,
                                                     const float* __restrict__ ew,
                                                     float* deg, int* cnt) {
    int e = blockIdx.x * 256 + threadIdx.x;
    if (e < NE) {
        int d = ei[NE + e];               // dst row of edge_index
        atomicAdd(&deg[d], ew[e]);
        atomicAdd(&cnt[d], 1);
    }
}

// ---------------- K3: dinv = deg^-0.5 ----------------
__global__ __launch_bounds__(256) void dinv_kernel(const float* __restrict__ deg,
                                                   float* __restrict__ dinv) {
    int i = blockIdx.x * 256 + threadIdx.x;
    if (i < NN) {
        float dg = deg[i];
        dinv[i] = dg > 0.f ? 1.0f / sqrtf(dg) : 0.f;
    }
}

// ---------------- K4: single-block exclusive scan of counts -> rowptr, cursor ----------------
__global__ __launch_bounds__(1024) void scan_kernel(const int* __restrict__ cnt,
                                                    int* __restrict__ rowp,
                                                    int* __restrict__ cur) {
    __shared__ int lds[1024];
    int tid = threadIdx.x;
    int base = 0;
    for (int start = 0; start < NN; start += 1024) {
        int i = start + tid;
        int v = (i < NN) ? cnt[i] : 0;
        lds[tid] = v;
        __syncthreads();
        for (int off = 1; off < 1024; off <<= 1) {
            int add = (tid >= off) ? lds[tid - off] : 0;
            __syncthreads();
            lds[tid] += add;
            __syncthreads();
        }
        int incl = lds[tid];
        int total = lds[1023];
        if (i < NN) { int ex = base + incl - v; rowp[i] = ex; cur[i] = ex; }
        base += total;
        __syncthreads();   // protect lds before next chunk overwrites
    }
    if (tid == 0) rowp[NN] = base;   // == NE
}

// ---------------- K5: scatter edges into CSR with normalized values ----------------
__global__ __launch_bounds__(256) void scatter_kernel(const int* __restrict__ ei,
                                                      const float* __restrict__ ew,
                                                      const float* __restrict__ dinv,
                                                      int* cur, int* __restrict__ ecol,
                                                      float* __restrict__ eval) {
    int e = blockIdx.x * 256 + threadIdx.x;
    if (e < NE) {
        int s = ei[e];
        int d = ei[NE + e];
        int pos = atomicAdd(&cur[d], 1);
        ecol[pos] = s;
        eval[pos] = dinv[s] * ew[e] * dinv[d];
    }
}

// ---------------- K6: fold tiny matrices + softmax into const block ----------------
// layout: Az0[0:12] Az1[12:24] cz[24:36] Ah0[36:48] Ah1[48:60] ch[60:72]
//         probs[72:84] W1[84:228] b1[228:240] W2[240:384] b2[384:396]
__global__ __launch_bounds__(256) void prep_kernel(const float* __restrict__ Wz, const float* __restrict__ bz,
                                                   const float* __restrict__ Wh, const float* __restrict__ bh,
                                                   const float* __restrict__ Lzw, const float* __restrict__ Lzb,
                                                   const float* __restrict__ Lhw, const float* __restrict__ Lhb,
                                                   const float* __restrict__ att,
                                                   const float* __restrict__ W1, const float* __restrict__ b1,
                                                   const float* __restrict__ W2, const float* __restrict__ b2,
                                                   float* __restrict__ cst) {
    int t = threadIdx.x;
    if (t < PP) {
        int p = t;
        float az0 = 0.f, az1 = 0.f, cz = 0.f, ah0 = 0.f, ah1 = 0.f, ch = 0.f;
        for (int q = 0; q < PP; ++q) {
            float lz = Lzw[q * PP + p], lh = Lhw[q * PP + p];
            az0 += Wz[q] * lz;        // Wz[0][q]
            az1 += Wz[PP + q] * lz;   // Wz[1][q]
            cz  += bz[q] * lz;
            ah0 += Wh[q] * lh;
            ah1 += Wh[PP + q] * lh;
            ch  += bh[q] * lh;
        }
        cz += Lzb[p]; ch += Lhb[p];
        cst[p] = az0; cst[12 + p] = az1; cst[24 + p] = cz;
        cst[36 + p] = ah0; cst[48 + p] = ah1; cst[60 + p] = ch;
        // softmax over attention
        float m = att[0];
        for (int q = 1; q < PP; ++q) m = fmaxf(m, att[q]);
        float ssum = 0.f;
        for (int q = 0; q < PP; ++q) ssum += __expf(att[q] - m);
        cst[72 + p] = __expf(att[p] - m) / ssum;
    }
    if (t < 144) { cst[84 + t] = W1[t]; cst[240 + t] = W2[t]; }
    if (t < PP) { cst[228 + t] = b1[t]; cst[384 + t] = b2[t]; }
}

// ---------------- K7: build X[N][384] (transposed, GAIN-filled) via LDS tiles ----------------
#define TILE 32
__global__ __launch_bounds__(256) void buildx_kernel(const float* __restrict__ x,
                                                     const float* __restrict__ mask,
                                                     const float* __restrict__ noise,
                                                     float* __restrict__ X) {
    __shared__ float tile[TILE][NCOL + 1];   // stride 385 -> conflict-free
    int tid = threadIdx.x;
    int n0 = blockIdx.x * TILE;
    int i = tid & 31;         // row in tile
    int prb = tid >> 5;       // 0..7
    #pragma unroll 4
    for (int it = 0; it < 24; ++it) {            // 192 (b,t) pairs / 8
        int pr = it * 8 + prb;                   // pr = b*12 + t
        int g = pr * NN + n0 + i;
        float m = mask[g];
        float xv = x[g];
        float nz = noise[g];
        float xf = m * xv + (1.f - m) * nz;      // GAIN fill (mask is exactly 0/1)
        int col = pr * 2;                        // == b*24 + t*2
        tile[i][col]     = xf;
        tile[i][col + 1] = m;
    }
    __syncthreads();
    #pragma unroll 4
    for (int it = 0; it < 48; ++it) {            // 32*384 / 256
        int idx = it * 256 + tid;
        int r = idx / NCOL;
        int c = idx - r * NCOL;
        X[(n0 + r) * NCOL + c] = tile[r][c];
    }
}

// ---------------- K8: gather SpMM: agg[dst] = dinv^2*X[dst] + sum norm_e * X[src] ----------------
__global__ __launch_bounds__(256) void spmm_kernel(const float* __restrict__ X,
                                                   const float* __restrict__ dinv,
                                                   const int* __restrict__ rowp,
                                                   const int* __restrict__ ecol,
                                                   const float* __restrict__ eval,
                                                   float* __restrict__ agg) {
    int wave = threadIdx.x >> 6;
    int lane = threadIdx.x & 63;
    int d = __builtin_amdgcn_readfirstlane(blockIdx.x * 4 + wave);  // force wave-uniform -> s_loads
    int r0 = rowp[d];
    int r1 = rowp[d + 1];
    float di = dinv[d];
    float acc[6];
    const float* xr = X + d * NCOL + lane;
    #pragma unroll
    for (int k = 0; k < 6; ++k) acc[k] = di * di * xr[k * 64];   // self-loop
    for (int e = r0; e < r1; ++e) {
        int s = ecol[e];
        float v = eval[e];
        const float* xs = X + s * NCOL + lane;
        #pragma unroll
        for (int k = 0; k < 6; ++k) acc[k] += v * xs[k * 64];
    }
    float* ag = agg + d * NCOL + lane;
    #pragma unroll
    for (int k = 0; k < 6; ++k) ag[k * 64] = acc[k];
}

// ---------------- K9: fused GRU(HO=0) + attention accum + MLP + outputs ----------------
__global__ __launch_bounds__(256) void pointwise_kernel(const float* __restrict__ agg,
                                                        const float* __restrict__ cst,
                                                        const float* __restrict__ x,
                                                        const float* __restrict__ mask,
                                                        float* __restrict__ out) {
    __shared__ float C[396];
    int tid = threadIdx.x;
    for (int i = tid; i < 396; i += 256) C[i] = cst[i];
    __syncthreads();
    int idx = blockIdx.x * 256 + tid;     // 1250*256 == BB*NN exactly
    int b = idx / NN;
    int n = idx - b * NN;
    float A[24];
    const float4* ap = (const float4*)(agg + (size_t)n * NCOL + b * 24);
    #pragma unroll
    for (int k = 0; k < 6; ++k) {
        float4 v = ap[k];
        A[4 * k + 0] = v.x; A[4 * k + 1] = v.y; A[4 * k + 2] = v.z; A[4 * k + 3] = v.w;
    }
    float h1[12];
    #pragma unroll
    for (int p = 0; p < 12; ++p) {
        float az0 = C[p], az1 = C[12 + p], czp = C[24 + p];
        float ah0 = C[36 + p], ah1 = C[48 + p], chp = C[60 + p];
        float hp = 0.f;
        #pragma unroll
        for (int t = 0; t < 12; ++t) {
            float a0 = A[2 * t], a1 = A[2 * t + 1];
            float z  = sigmoidf_(a0 * az0 + a1 * az1 + czp);
            float th = tanh_fast(a0 * ah0 + a1 * ah1 + chp);
            hp += C[72 + t] * ((1.f - z) * th);   // H = (1-Z)*Ht since H0 == 0
        }
        h1[p] = fmaxf(hp, 0.f);                   // relu(H_accum)
    }
    float h2[12];
    #pragma unroll
    for (int p = 0; p < 12; ++p) {
        float s = C[228 + p];
        #pragma unroll
        for (int q = 0; q < 12; ++q) s += h1[q] * C[84 + q * 12 + p];
        h2[p] = fmaxf(s, 0.f);
    }
    #pragma unroll
    for (int p = 0; p < 12; ++p) {
        float s = C[384 + p];
        #pragma unroll
        for (int q = 0; q < 12; ++q) s += h2[q] * C[240 + q * 12 + p];
        float imp = sigmoidf_(s);
        int o = (b * PP + p) * NN + n;
        float m = mask[o];
        float xv = x[o];
        out[o] = m * xv + (1.f - m) * imp;        // mask exactly 0/1 -> mask*x_fill == mask*x
        out[OUT_OFF + o] = imp;
    }
}

// ---------------- launcher ----------------
extern "C" void kernel_launch(void* const* d_in, const int* in_sizes, int n_in,
                              void* d_out, int out_size, void* d_ws, size_t ws_size,
                              hipStream_t stream) {
    const float* x     = (const float*)d_in[0];
    const float* mask  = (const float*)d_in[1];
    const float* noise = (const float*)d_in[2];
    const int*   ei    = (const int*)d_in[3];
    const float* ew    = (const float*)d_in[4];
    const float* Wz    = (const float*)d_in[5];
    const float* bz    = (const float*)d_in[6];
    // d_in[7]=Wr, d_in[8]=br unused (H0==0 -> R unused)
    const float* Wh    = (const float*)d_in[9];
    const float* bh    = (const float*)d_in[10];
    const float* Lzw   = (const float*)d_in[11];
    const float* Lzb   = (const float*)d_in[12];
    // d_in[13]=Lr_w, d_in[14]=Lr_b unused
    const float* Lhw   = (const float*)d_in[15];
    const float* Lhb   = (const float*)d_in[16];
    const float* att   = (const float*)d_in[17];
    const float* W1    = (const float*)d_in[18];
    const float* b1    = (const float*)d_in[19];
    const float* W2    = (const float*)d_in[20];
    const float* b2    = (const float*)d_in[21];
    float* out = (float*)d_out;

    // workspace carve-up (~64.5 MB)
    float* Xf   = (float*)d_ws;                     // NN*NCOL
    float* AGG  = Xf + (size_t)NN * NCOL;           // NN*NCOL
    float* DEG  = AGG + (size_t)NN * NCOL;          // NN
    float* DINV = DEG + NN;                         // NN
    float* EVAL = DINV + NN;                        // NE
    float* CST  = EVAL + NE;                        // 512
    int*   CNT  = (int*)(CST + 512);                // NN
    int*   ROWP = CNT + NN;                         // NN+1
    int*   CUR  = ROWP + NN + 1;                    // NN
    int*   ECOL = CUR + NN;                         // NE

    hipLaunchKernelGGL(init_kernel,    dim3((NN + 255) / 256), dim3(256), 0, stream, DEG, CNT);
    hipLaunchKernelGGL(degcnt_kernel,  dim3((NE + 255) / 256), dim3(256), 0, stream, ei, ew, DEG, CNT);
    hipLaunchKernelGGL(dinv_kernel,    dim3((NN + 255) / 256), dim3(256), 0, stream, DEG, DINV);
    hipLaunchKernelGGL(scan_kernel,    dim3(1), dim3(1024), 0, stream, CNT, ROWP, CUR);
    hipLaunchKernelGGL(scatter_kernel, dim3((NE + 255) / 256), dim3(256), 0, stream, ei, ew, DINV, CUR, ECOL, EVAL);
    hipLaunchKernelGGL(prep_kernel,    dim3(1), dim3(256), 0, stream,
                       Wz, bz, Wh, bh, Lzw, Lzb, Lhw, Lhb, att, W1, b1, W2, b2, CST);
    hipLaunchKernelGGL(buildx_kernel,  dim3(NN / TILE), dim3(256), 0, stream, x, mask, noise, Xf);
    hipLaunchKernelGGL(spmm_kernel,    dim3(NN / 4), dim3(256), 0, stream, Xf, DINV, ROWP, ECOL, EVAL, AGG);
    hipLaunchKernelGGL(pointwise_kernel, dim3((BB * NN) / 256), dim3(256), 0, stream, AGG, CST, x, mask, out);
}